// Round 3
// baseline (414.943 us; speedup 1.0000x reference)
//
#include <hip/hip_runtime.h>
#include <hip/hip_bf16.h>

typedef unsigned short u16;
using bf16x8 = __bf16 __attribute__((ext_vector_type(8)));
using f32x4  = float  __attribute__((ext_vector_type(4)));

#define BB 4
#define TT 4096
#define DD 1024
#define MROWS (BB*TT)   /* 16384 */
#define CT 64           /* scan chunk length */
#define NC (TT/CT)      /* 64 chunks */

__device__ __forceinline__ float sigm(float x) { return 1.0f / (1.0f + __expf(-x)); }
__device__ __forceinline__ u16 f2bf(float f) {
    __hip_bfloat16 h = __float2bfloat16(f);
    return *reinterpret_cast<u16*>(&h);
}
__device__ __forceinline__ float bf2f(u16 u) { return __uint_as_float(((unsigned)u) << 16); }

// async 16B global->LDS (direct-to-shared DMA; LDS dest must be wave-uniform base + lane*16)
__device__ __forceinline__ void async_cp16(const u16* g, u16* l) {
    __builtin_amdgcn_global_load_lds(
        (const __attribute__((address_space(1))) unsigned int*)g,
        (__attribute__((address_space(3))) unsigned int*)l, 16, 0, 0);
}

// ---------------------------------------------------------------- converts
__global__ __launch_bounds__(256) void conv_x_kernel(const float* __restrict__ s,
                                                     u16* __restrict__ d) {
    size_t i = (size_t)blockIdx.x * 256 + threadIdx.x;   // one float4 per thread
    float4 v = *(const float4*)(s + i * 4);
    ushort4 u;
    u.x = f2bf(v.x); u.y = f2bf(v.y); u.z = f2bf(v.z); u.w = f2bf(v.w);
    *(ushort4*)(d + i * 4) = u;
}

__global__ __launch_bounds__(256) void conv_w4_kernel(const float* __restrict__ w0,
                                                      const float* __restrict__ w1,
                                                      const float* __restrict__ w2,
                                                      const float* __restrict__ w3,
                                                      u16* __restrict__ dst) {
    int i = blockIdx.x * 256 + threadIdx.x;  // 0 .. 4*2^18-1 float4s
    int sel = i >> 18;                       // 2^18 float4 per 1024x1024 weight
    int off = i & 262143;
    const float* s = (sel == 0) ? w0 : (sel == 1) ? w1 : (sel == 2) ? w2 : w3;
    float4 v = *(const float4*)(s + (size_t)off * 4);
    ushort4 u;
    u.x = f2bf(v.x); u.y = f2bf(v.y); u.z = f2bf(v.z); u.w = f2bf(v.w);
    *(ushort4*)(dst + ((size_t)sel << 20) + (size_t)off * 4) = u;
}

// ---------------------------------------------------------------- GEMM
// C[m][n] = sum_k A[m][k] * W[n][k], A:[M,K] bf16 row-major, W:[N,K] bf16 row-major.
// 128x128 tile, BK=64, 4 waves (2x2), each wave 64x64 via 4x4 mfma_f32_16x16x32_bf16.
// LDS XOR-swizzle: physical granule p of row m holds logical k-granule p^(m&7)
// (swizzle applied on the GLOBAL address side so global_load_lds's
//  wave-uniform-base+lane*16 LDS pattern is contiguous). 0 bank conflicts measured.
// XCD chunk-swizzle (bijective, nwg%8==0): each XCD gets a contiguous y-band so an
// A-panel is fetched by one XCD's L2 once instead of streamed 8x through L3.
#define BM 128
#define BN 128
#define BK 64

template <typename OutT>
__global__ __launch_bounds__(256, 2)
void gemm_bf16_bt(const u16* __restrict__ Ag, const u16* __restrict__ Bg, int K,
                  OutT* __restrict__ P0, OutT* __restrict__ P1, OutT* __restrict__ P2) {
    __shared__ u16 As[BM * BK];
    __shared__ u16 Bs[BN * BK];

    const int tid  = threadIdx.x;
    const int lane = tid & 63;
    const int wid  = tid >> 6;
    const int wm   = wid >> 1;      // wave row 0..1
    const int wn   = wid & 1;       // wave col 0..1
    const int lr   = lane & 15;
    const int lq   = lane >> 4;

    // bijective XCD swizzle on the flat block index (nwg divisible by 8)
    const int nwg  = gridDim.x * gridDim.y;
    const int flat = blockIdx.y * gridDim.x + blockIdx.x;
    const int cpx  = nwg >> 3;
    const int swz  = (flat & 7) * cpx + (flat >> 3);
    const int bx   = swz % gridDim.x;
    const int by   = swz / gridDim.x;

    const long bM  = (long)by * BM;
    const long bN0 = (long)bx * BN;

    const f32x4 zero = {0.f, 0.f, 0.f, 0.f};
    f32x4 acc[4][4];
#pragma unroll
    for (int i = 0; i < 4; i++)
#pragma unroll
        for (int j = 0; j < 4; j++) acc[i][j] = zero;

    for (int kt = 0; kt < K; kt += BK) {
        __syncthreads();
#pragma unroll
        for (int j = 0; j < 4; j++) {
            const int G  = j * 256 + tid;     // LDS granule = wave_base + lane (contiguous)
            const int m  = G >> 3;            // row 0..127
            const int p  = G & 7;             // physical granule
            const int gk = p ^ (m & 7);       // logical k-granule (swizzle on global side)
            async_cp16(Ag + (bM + m) * K + kt + gk * 8, &As[G * 8]);
            async_cp16(Bg + (bN0 + m) * K + kt + gk * 8, &Bs[G * 8]);
        }
        __syncthreads();   // compiler emits s_waitcnt vmcnt(0) before s_barrier
#pragma unroll
        for (int kk = 0; kk < BK / 32; kk++) {
            bf16x8 av[4], bv[4];
#pragma unroll
            for (int f = 0; f < 4; f++) {
                const int am = wm * 64 + f * 16 + lr;
                const int ag = (kk * 4 + lq) ^ (am & 7);
                av[f] = *(const bf16x8*)(&As[am * 64 + ag * 8]);
                const int bn = wn * 64 + f * 16 + lr;
                const int bg = (kk * 4 + lq) ^ (bn & 7);
                bv[f] = *(const bf16x8*)(&Bs[bn * 64 + bg * 8]);
            }
#pragma unroll
            for (int i = 0; i < 4; i++)
#pragma unroll
                for (int j = 0; j < 4; j++)
                    acc[i][j] = __builtin_amdgcn_mfma_f32_16x16x32_bf16(av[i], bv[j],
                                                                        acc[i][j], 0, 0, 0);
        }
    }

    const int pl = (int)(bN0 >> 10);   // BN=128 divides 1024 -> whole block in one plane
    OutT* P = (pl == 0) ? P0 : ((pl == 1) ? P1 : P2);
    const int cn = (int)(bN0 & 1023);
#pragma unroll
    for (int i = 0; i < 4; i++) {
        const long m0 = bM + wm * 64 + i * 16 + lq * 4;
#pragma unroll
        for (int j = 0; j < 4; j++) {
            const int n = cn + wn * 64 + j * 16 + lr;
#pragma unroll
            for (int r = 0; r < 4; r++) {
                if constexpr (sizeof(OutT) == 2)
                    P[(m0 + r) * 1024 + n] = f2bf(acc[i][j][r]);
                else
                    P[(m0 + r) * 1024 + n] = acc[i][j][r];
            }
        }
    }
}

// ---------------------------------------------------------------- chunked scan
// h_t = f_t * h_{t-1} + silu(i_t)*(1-f_t),  f = sigmoid(f_pre); planes are bf16
__global__ __launch_bounds__(256) void scan_pass1(const u16* __restrict__ ip,
                                                  const u16* __restrict__ fp,
                                                  float* __restrict__ Fc,
                                                  float* __restrict__ Ic) {
    const int tid = blockIdx.x * 256 + threadIdx.x;  // B*NC*D/4 = 65536 threads
    const int d4  = tid & 255;                       // d/4
    const int c   = (tid >> 8) & (NC - 1);
    const int b   = tid >> 14;
    size_t base = ((size_t)(b * TT + c * CT) << 10) + (size_t)d4 * 4;
    float F[4] = {1.f, 1.f, 1.f, 1.f};
    float I[4] = {0.f, 0.f, 0.f, 0.f};
#pragma unroll 8
    for (int t = 0; t < CT; t++) {
        ushort4 fu = *(const ushort4*)(fp + base);
        ushort4 iu = *(const ushort4*)(ip + base);
        base += DD;
        const u16 fa[4] = {fu.x, fu.y, fu.z, fu.w};
        const u16 ia[4] = {iu.x, iu.y, iu.z, iu.w};
#pragma unroll
        for (int j = 0; j < 4; j++) {
            float f  = sigm(bf2f(fa[j]));
            float iv = bf2f(ia[j]);
            float v  = iv * sigm(iv) * (1.f - f);
            I[j] = fmaf(f, I[j], v);
            F[j] *= f;
        }
    }
    const size_t o = (((size_t)(b * NC + c)) << 10) + (size_t)d4 * 4;
    float4 vF = {F[0], F[1], F[2], F[3]};
    float4 vI = {I[0], I[1], I[2], I[3]};
    *(float4*)(Fc + o) = vF;
    *(float4*)(Ic + o) = vI;
}

// pass2: exclusive scan over the 64 chunks via in-wave Kogge-Stone.
__global__ __launch_bounds__(256) void scan_pass2(const float* __restrict__ Fc,
                                                  const float* __restrict__ Ic,
                                                  float* __restrict__ Hin) {
    const int gtid = blockIdx.x * 256 + threadIdx.x;   // B*D*64 = 262144 threads
    const int lane = gtid & 63;                        // chunk c
    const int w    = gtid >> 6;                        // wave id = (b,d)
    const int b    = w >> 10;
    const int d    = w & 1023;
    const int idx  = ((b * NC + lane) << 10) + d;
    float F = Fc[idx];
    float I = Ic[idx];
#pragma unroll
    for (int s = 1; s < 64; s <<= 1) {
        float Fp = __shfl_up(F, s, 64);
        float Ip = __shfl_up(I, s, 64);
        if (lane >= s) {
            I = fmaf(Ip, F, I);   // use pre-update F
            F *= Fp;
        }
    }
    float Hex = __shfl_up(I, 1, 64);
    if (lane == 0) Hex = 0.f;
    Hin[idx] = Hex;
}

// pass3 fused with RMSNorm*swish(g): a block covers one (b,chunk) and FULL D
// (256 thr x 4 d). Per t: recompute h (fp32), block-reduce sum(h^2), then write
// o = h*rsqrt(mean+eps)*w * g*sigm(g) directly. Kills the h bf16 round-trip and
// the separate rmsnorm launch; RMS uses un-rounded fp32 h (closer to reference).
__global__ __launch_bounds__(256) void scan_pass3_norm(const u16* __restrict__ ip,
                                                       const u16* __restrict__ fp,
                                                       const float* __restrict__ Hin,
                                                       const u16* __restrict__ gp,
                                                       const float* __restrict__ w,
                                                       u16* __restrict__ oout) {
    const int t_ = threadIdx.x;            // d4 index
    const int c  = blockIdx.x & (NC - 1);
    const int b  = blockIdx.x >> 6;        // NC = 64
    size_t base = ((size_t)(b * TT + c * CT) << 10) + (size_t)t_ * 4;
    const size_t o = (((size_t)(b * NC + c)) << 10) + (size_t)t_ * 4;
    float4 hv = *(const float4*)(Hin + o);
    float h[4] = {hv.x, hv.y, hv.z, hv.w};
    const float4 wv = *(const float4*)(w + (size_t)t_ * 4);
    const float wl[4] = {wv.x, wv.y, wv.z, wv.w};
    __shared__ float red[2][4];
    for (int t = 0; t < CT; t++) {
        ushort4 fu = *(const ushort4*)(fp + base);
        ushort4 iu = *(const ushort4*)(ip + base);
        ushort4 gu = *(const ushort4*)(gp + base);
        const u16 fa[4] = {fu.x, fu.y, fu.z, fu.w};
        const u16 ia[4] = {iu.x, iu.y, iu.z, iu.w};
        const u16 ga[4] = {gu.x, gu.y, gu.z, gu.w};
        float ss = 0.f;
#pragma unroll
        for (int j = 0; j < 4; j++) {
            float f  = sigm(bf2f(fa[j]));
            float iv = bf2f(ia[j]);
            float v  = iv * sigm(iv) * (1.f - f);
            h[j] = fmaf(f, h[j], v);
            ss = fmaf(h[j], h[j], ss);
        }
#pragma unroll
        for (int off = 32; off > 0; off >>= 1) ss += __shfl_down(ss, off);
        if ((t_ & 63) == 0) red[t & 1][t_ >> 6] = ss;
        __syncthreads();
        const float tot = red[t & 1][0] + red[t & 1][1] + red[t & 1][2] + red[t & 1][3];
        const float rms = rsqrtf(tot * (1.f / 1024.f) + 1e-5f);
        ushort4 ou;
        u16 oa[4];
#pragma unroll
        for (int j = 0; j < 4; j++) {
            float gv = bf2f(ga[j]);
            oa[j] = f2bf(h[j] * rms * wl[j] * gv * sigm(gv));
        }
        ou.x = oa[0]; ou.y = oa[1]; ou.z = oa[2]; ou.w = oa[3];
        *(ushort4*)(oout + base) = ou;
        base += DD;
    }
}

// ---------------------------------------------------------------- launch
extern "C" void kernel_launch(void* const* d_in, const int* in_sizes, int n_in,
                              void* d_out, int out_size, void* d_ws, size_t ws_size,
                              hipStream_t stream) {
    const float* x  = (const float*)d_in[0];
    const float* Wi = (const float*)d_in[1];
    const float* Wf = (const float*)d_in[2];
    const float* Wg = (const float*)d_in[3];
    const float* Wo = (const float*)d_in[4];
    const float* nw = (const float*)d_in[5];
    float* out = (float*)d_out;

    const size_t MB = 1ull << 20;
    char* ws = (char*)d_ws;
    u16*   xo  = (u16*)(ws);              // 32MB: x_bf16, later o_bf16
    u16*   Wb  = (u16*)(ws + 32 * MB);    // 8MB: [Wi;Wf;Wg;Wo] bf16, K-major rows
    u16*   Pi  = (u16*)(ws + 40 * MB);    // 32MB: i_pre bf16
    u16*   Pf  = (u16*)(ws + 72 * MB);    // 32MB: f_pre bf16
    float* Fc  = (float*)(ws + 104 * MB); // 1MB
    float* Ic  = Fc + BB * NC * DD;       // 1MB
    float* Hin = Ic + BB * NC * DD;       // 1MB
    u16*   g   = (u16*)d_out;             // g plane (bf16) parked in d_out until final GEMM

    conv_x_kernel<<<16384, 256, 0, stream>>>(x, xo);
    conv_w4_kernel<<<4096, 256, 0, stream>>>(Wi, Wf, Wg, Wo, Wb);
    // i_pre / f_pre / g in one GEMM: N=3072
    gemm_bf16_bt<u16><<<dim3(24, 128), 256, 0, stream>>>(xo, Wb, 1024, Pi, Pf, g);
    scan_pass1<<<256, 256, 0, stream>>>(Pi, Pf, Fc, Ic);
    scan_pass2<<<1024, 256, 0, stream>>>(Fc, Ic, Hin);
    // fused scan finish + RMSNorm*swish(g): writes o into xo
    scan_pass3_norm<<<256, 256, 0, stream>>>(Pi, Pf, Hin, g, nw, xo);
    // out = o @ Wo^T
    gemm_bf16_bt<float><<<dim3(8, 128), 256, 0, stream>>>(xo, Wb + 3ull * 1024 * 1024, 1024,
                                                          out, out, out);
}

// Round 4
// 389.532 us; speedup vs baseline: 1.0652x; 1.0652x over previous
//
#include <hip/hip_runtime.h>
#include <hip/hip_bf16.h>

typedef unsigned short u16;
using bf16x8 = __bf16 __attribute__((ext_vector_type(8)));
using f32x4  = float  __attribute__((ext_vector_type(4)));

#define BB 4
#define TT 4096
#define DD 1024
#define MROWS (BB*TT)   /* 16384 */
#define CT 64           /* scan chunk length */
#define NC (TT/CT)      /* 64 chunks */

__device__ __forceinline__ float sigm(float x) { return 1.0f / (1.0f + __expf(-x)); }
__device__ __forceinline__ u16 f2bf(float f) {
    __hip_bfloat16 h = __float2bfloat16(f);
    return *reinterpret_cast<u16*>(&h);
}
__device__ __forceinline__ float bf2f(u16 u) { return __uint_as_float(((unsigned)u) << 16); }

// async 16B global->LDS (direct-to-shared DMA; LDS dest must be wave-uniform base + lane*16)
__device__ __forceinline__ void async_cp16(const u16* g, u16* l) {
    __builtin_amdgcn_global_load_lds(
        (const __attribute__((address_space(1))) unsigned int*)g,
        (__attribute__((address_space(3))) unsigned int*)l, 16, 0, 0);
}

// ---------------------------------------------------------------- converts
__global__ __launch_bounds__(256) void conv_x_kernel(const float* __restrict__ s,
                                                     u16* __restrict__ d) {
    size_t i = (size_t)blockIdx.x * 256 + threadIdx.x;   // one float4 per thread
    float4 v = *(const float4*)(s + i * 4);
    ushort4 u;
    u.x = f2bf(v.x); u.y = f2bf(v.y); u.z = f2bf(v.z); u.w = f2bf(v.w);
    *(ushort4*)(d + i * 4) = u;
}

__global__ __launch_bounds__(256) void conv_w4_kernel(const float* __restrict__ w0,
                                                      const float* __restrict__ w1,
                                                      const float* __restrict__ w2,
                                                      const float* __restrict__ w3,
                                                      u16* __restrict__ dst) {
    int i = blockIdx.x * 256 + threadIdx.x;  // 0 .. 4*2^18-1 float4s
    int sel = i >> 18;                       // 2^18 float4 per 1024x1024 weight
    int off = i & 262143;
    const float* s = (sel == 0) ? w0 : (sel == 1) ? w1 : (sel == 2) ? w2 : w3;
    float4 v = *(const float4*)(s + (size_t)off * 4);
    ushort4 u;
    u.x = f2bf(v.x); u.y = f2bf(v.y); u.z = f2bf(v.z); u.w = f2bf(v.w);
    *(ushort4*)(dst + ((size_t)sel << 20) + (size_t)off * 4) = u;
}

// ---------------------------------------------------------------- GEMM 128^2 (proven)
// C[m][n] = sum_k A[m][k] * W[n][k]. Default blockIdx mapping (XCD swizzle measured
// harmful here: FETCH 143->232MB in R3). 0 bank conflicts via granule^row XOR swizzle.
#define BM 128
#define BN 128
#define BK 64

template <typename OutT>
__global__ __launch_bounds__(256, 2)
void gemm_bf16_bt(const u16* __restrict__ Ag, const u16* __restrict__ Bg, int K,
                  OutT* __restrict__ P0, OutT* __restrict__ P1, OutT* __restrict__ P2) {
    __shared__ u16 As[BM * BK];
    __shared__ u16 Bs[BN * BK];

    const int tid  = threadIdx.x;
    const int lane = tid & 63;
    const int wid  = tid >> 6;
    const int wm   = wid >> 1;      // wave row 0..1
    const int wn   = wid & 1;       // wave col 0..1
    const int lr   = lane & 15;
    const int lq   = lane >> 4;

    const long bM  = (long)blockIdx.y * BM;
    const long bN0 = (long)blockIdx.x * BN;

    const f32x4 zero = {0.f, 0.f, 0.f, 0.f};
    f32x4 acc[4][4];
#pragma unroll
    for (int i = 0; i < 4; i++)
#pragma unroll
        for (int j = 0; j < 4; j++) acc[i][j] = zero;

    for (int kt = 0; kt < K; kt += BK) {
        __syncthreads();
#pragma unroll
        for (int j = 0; j < 4; j++) {
            const int G  = j * 256 + tid;     // LDS granule = wave_base + lane (contiguous)
            const int m  = G >> 3;            // row 0..127
            const int p  = G & 7;             // physical granule
            const int gk = p ^ (m & 7);       // logical k-granule (swizzle on global side)
            async_cp16(Ag + (bM + m) * K + kt + gk * 8, &As[G * 8]);
            async_cp16(Bg + (bN0 + m) * K + kt + gk * 8, &Bs[G * 8]);
        }
        __syncthreads();
#pragma unroll
        for (int kk = 0; kk < BK / 32; kk++) {
            bf16x8 av[4], bv[4];
#pragma unroll
            for (int f = 0; f < 4; f++) {
                const int am = wm * 64 + f * 16 + lr;
                const int ag = (kk * 4 + lq) ^ (am & 7);
                av[f] = *(const bf16x8*)(&As[am * 64 + ag * 8]);
                const int bn = wn * 64 + f * 16 + lr;
                const int bg = (kk * 4 + lq) ^ (bn & 7);
                bv[f] = *(const bf16x8*)(&Bs[bn * 64 + bg * 8]);
            }
#pragma unroll
            for (int i = 0; i < 4; i++)
#pragma unroll
                for (int j = 0; j < 4; j++)
                    acc[i][j] = __builtin_amdgcn_mfma_f32_16x16x32_bf16(av[i], bv[j],
                                                                        acc[i][j], 0, 0, 0);
        }
    }

    const int pl = (int)(bN0 >> 10);
    OutT* P = (pl == 0) ? P0 : ((pl == 1) ? P1 : P2);
    const int cn = (int)(bN0 & 1023);
#pragma unroll
    for (int i = 0; i < 4; i++) {
        const long m0 = bM + wm * 64 + i * 16 + lq * 4;
#pragma unroll
        for (int j = 0; j < 4; j++) {
            const int n = cn + wn * 64 + j * 16 + lr;
#pragma unroll
            for (int r = 0; r < 4; r++) {
                if constexpr (sizeof(OutT) == 2)
                    P[(m0 + r) * 1024 + n] = f2bf(acc[i][j][r]);
                else
                    P[(m0 + r) * 1024 + n] = acc[i][j][r];
            }
        }
    }
}

// ---------------------------------------------------------------- GEMM 256^2 8-phase (asm ds_read)
// R2's schedule (ledger verified, passed) but fragment reads are inline-asm ds_read_b128
// so the compiler's waitcnt legalizer cannot see LDS reads aliasing the global_load_lds
// destinations -> no conservative vmcnt(0) drains per phase; our counted vmcnt(4) per
// K-tile is the only VMEM wait. Rule #18: lgkmcnt(0) is followed by sched_barrier(0) so
// MFMAs cannot hoist above the wait. XOR-granule swizzle: kk=1 address = kk=0 addr ^ 64.
#define DSR(dst, a, OFF) \
    asm volatile("ds_read_b128 %0, %1 offset:" OFF : "=v"(dst) : "v"(a))

#define READ_A_ASM(dst, MH) { \
    const unsigned a0 = asB + (unsigned)(p << 15) + ((MH) << 14) \
                        + (wm * 64 + lr) * 128 + ((lq ^ lr7) << 4); \
    const unsigned a1 = a0 ^ 64; \
    DSR(dst[0][0], a0, "0");    DSR(dst[1][0], a0, "2048"); \
    DSR(dst[2][0], a0, "4096"); DSR(dst[3][0], a0, "6144"); \
    DSR(dst[0][1], a1, "0");    DSR(dst[1][1], a1, "2048"); \
    DSR(dst[2][1], a1, "4096"); DSR(dst[3][1], a1, "6144"); }

#define READ_B_ASM(dst, NH) { \
    const unsigned b0 = bsB + (unsigned)(p << 15) + ((NH) << 14) \
                        + (wn * 32 + lr) * 128 + ((lq ^ lr7) << 4); \
    const unsigned b1 = b0 ^ 64; \
    DSR(dst[0][0], b0, "0");    DSR(dst[1][0], b0, "2048"); \
    DSR(dst[0][1], b1, "0");    DSR(dst[1][1], b1, "2048"); }

#define MFMA16(AV, BV, MH, NH)                                                  \
  { _Pragma("unroll") for (int kk = 0; kk < 2; kk++)                            \
    _Pragma("unroll") for (int f = 0; f < 4; f++)                               \
    _Pragma("unroll") for (int j = 0; j < 2; j++)                               \
      acc[(MH)*4+f][(NH)*2+j] = __builtin_amdgcn_mfma_f32_16x16x32_bf16(        \
          AV[f][kk], BV[j][kk], acc[(MH)*4+f][(NH)*2+j], 0, 0, 0); }

#define SYNC_PRE()                                                              \
  do { __builtin_amdgcn_s_barrier();                                            \
       asm volatile("s_waitcnt lgkmcnt(0)" ::: "memory");                       \
       __builtin_amdgcn_sched_barrier(0);                                       \
       __builtin_amdgcn_s_setprio(1); } while (0)
#define SYNC_POST()                                                             \
  do { __builtin_amdgcn_s_setprio(0);                                           \
       __builtin_amdgcn_s_barrier(); } while (0)

template <typename OutT>
__global__ __launch_bounds__(512, 2)
void gemm256a(const u16* __restrict__ Ag, const u16* __restrict__ Bg, int K,
              OutT* __restrict__ P0, OutT* __restrict__ P1, OutT* __restrict__ P2) {
    __shared__ u16 As[32768];   // [buf 2][half 2][rl 128][granule 8][8] = 64KB
    __shared__ u16 Bs[32768];

    const int tid  = threadIdx.x;
    const int lane = tid & 63;
    const int wid  = tid >> 6;       // 0..7
    const int wm   = wid >> 2;       // wave row 0..1
    const int wn   = wid & 3;        // wave col 0..3
    const int lr   = lane & 15;
    const int lq   = lane >> 4;
    const int lr7  = lr & 7;

    const unsigned asB = (unsigned)(uintptr_t)&As[0];   // LDS aperture is 4GB-aligned
    const unsigned bsB = (unsigned)(uintptr_t)&Bs[0];

    const long bM  = (long)blockIdx.y * 256;
    const long bN0 = (long)blockIdx.x * 256;
    const int  KT  = K >> 6;

    auto stageA = [&](int cc, int h) {
#pragma unroll
        for (int l = 0; l < 2; l++) {
            const int G  = l * 512 + tid;
            const int rl = G >> 3;
            const int gk = (G & 7) ^ (rl & 7);
            const int r  = (rl & 63) + h * 64 + ((rl >> 6) << 7);  // rows: bit6 == h
            async_cp16(Ag + (bM + r) * K + cc * 64 + gk * 8,
                       &As[(((cc & 1) * 2 + h) << 13) + G * 8]);
        }
    };
    auto stageB = [&](int cc, int h) {
#pragma unroll
        for (int l = 0; l < 2; l++) {
            const int G  = l * 512 + tid;
            const int rl = G >> 3;
            const int gk = (G & 7) ^ (rl & 7);
            const int r  = (rl & 31) + h * 32 + ((rl >> 5) << 6);  // rows: bit5 == h
            async_cp16(Bg + (bN0 + r) * K + cc * 64 + gk * 8,
                       &Bs[(((cc & 1) * 2 + h) << 13) + G * 8]);
        }
    };

    const f32x4 zero = {0.f, 0.f, 0.f, 0.f};
    f32x4 acc[8][4];
#pragma unroll
    for (int i = 0; i < 8; i++)
#pragma unroll
        for (int j = 0; j < 4; j++) acc[i][j] = zero;

    // prologue: tile0 fully + first two halves of tile1 (issue order = retirement order)
    stageA(0, 0); stageB(0, 0); stageA(0, 1); stageB(0, 1);
    if (KT > 1) {
        stageA(1, 0); stageB(1, 0);
        asm volatile("s_waitcnt vmcnt(4)" ::: "memory");   // tile0 landed; tile1 A0/B0 in flight
    } else {
        asm volatile("s_waitcnt vmcnt(0)" ::: "memory");
    }
    __builtin_amdgcn_s_barrier();

    for (int c = 0; c < KT; ++c) {
        const int  p  = c & 1;
        const bool s1 = (c + 1 < KT);
        const bool s2 = (c + 2 < KT);
        bf16x8 av0[4][2], av1[4][2], bv0[2][2], bv1[2][2];
        // P1: quadrant (0,0)
        READ_A_ASM(av0, 0); READ_B_ASM(bv0, 0);
        if (s1) stageA(c + 1, 1);
        SYNC_PRE(); MFMA16(av0, bv0, 0, 0); SYNC_POST();
        // P2: quadrant (0,1)  (av0 retained in regs)
        READ_B_ASM(bv1, 1);
        if (s1) stageB(c + 1, 1);
        SYNC_PRE(); MFMA16(av0, bv1, 0, 1); SYNC_POST();
        // P3: quadrant (1,0)  (bv0 retained)
        READ_A_ASM(av1, 1);
        if (s2) stageA(c + 2, 0);
        SYNC_PRE(); MFMA16(av1, bv0, 1, 0); SYNC_POST();
        // P4: quadrant (1,1)  (av1, bv1 retained; no ds_reads)
        if (s2) {
            stageB(c + 2, 0);
            asm volatile("s_waitcnt vmcnt(4)" ::: "memory");  // tile c+1 fully landed
        } else if (s1) {
            asm volatile("s_waitcnt vmcnt(0)" ::: "memory");
        }
        SYNC_PRE(); MFMA16(av1, bv1, 1, 1); SYNC_POST();
    }

    const int pl = (int)(bN0 >> 10);
    OutT* P = (pl == 0) ? P0 : ((pl == 1) ? P1 : P2);
    const int cn = (int)(bN0 & 1023);
#pragma unroll
    for (int i = 0; i < 8; i++) {
        const long m0 = bM + wm * 128 + i * 16 + lq * 4;
#pragma unroll
        for (int j = 0; j < 4; j++) {
            const int n = cn + wn * 64 + j * 16 + lr;
#pragma unroll
            for (int r = 0; r < 4; r++) {
                if constexpr (sizeof(OutT) == 2)
                    P[(m0 + r) * 1024 + n] = f2bf(acc[i][j][r]);
                else
                    P[(m0 + r) * 1024 + n] = acc[i][j][r];
            }
        }
    }
}

// ---------------------------------------------------------------- chunked scan
__global__ __launch_bounds__(256) void scan_pass1(const u16* __restrict__ ip,
                                                  const u16* __restrict__ fp,
                                                  float* __restrict__ Fc,
                                                  float* __restrict__ Ic) {
    const int tid = blockIdx.x * 256 + threadIdx.x;  // B*NC*D/4 = 65536 threads
    const int d4  = tid & 255;
    const int c   = (tid >> 8) & (NC - 1);
    const int b   = tid >> 14;
    size_t base = ((size_t)(b * TT + c * CT) << 10) + (size_t)d4 * 4;
    float F[4] = {1.f, 1.f, 1.f, 1.f};
    float I[4] = {0.f, 0.f, 0.f, 0.f};
#pragma unroll 8
    for (int t = 0; t < CT; t++) {
        ushort4 fu = *(const ushort4*)(fp + base);
        ushort4 iu = *(const ushort4*)(ip + base);
        base += DD;
        const u16 fa[4] = {fu.x, fu.y, fu.z, fu.w};
        const u16 ia[4] = {iu.x, iu.y, iu.z, iu.w};
#pragma unroll
        for (int j = 0; j < 4; j++) {
            float f  = sigm(bf2f(fa[j]));
            float iv = bf2f(ia[j]);
            float v  = iv * sigm(iv) * (1.f - f);
            I[j] = fmaf(f, I[j], v);
            F[j] *= f;
        }
    }
    const size_t o = (((size_t)(b * NC + c)) << 10) + (size_t)d4 * 4;
    float4 vF = {F[0], F[1], F[2], F[3]};
    float4 vI = {I[0], I[1], I[2], I[3]};
    *(float4*)(Fc + o) = vF;
    *(float4*)(Ic + o) = vI;
}

__global__ __launch_bounds__(256) void scan_pass2(const float* __restrict__ Fc,
                                                  const float* __restrict__ Ic,
                                                  float* __restrict__ Hin) {
    const int gtid = blockIdx.x * 256 + threadIdx.x;   // B*D*64 = 262144 threads
    const int lane = gtid & 63;                        // chunk c
    const int w    = gtid >> 6;                        // wave id = (b,d)
    const int b    = w >> 10;
    const int d    = w & 1023;
    const int idx  = ((b * NC + lane) << 10) + d;
    float F = Fc[idx];
    float I = Ic[idx];
#pragma unroll
    for (int s = 1; s < 64; s <<= 1) {
        float Fp = __shfl_up(F, s, 64);
        float Ip = __shfl_up(I, s, 64);
        if (lane >= s) {
            I = fmaf(Ip, F, I);
            F *= Fp;
        }
    }
    float Hex = __shfl_up(I, 1, 64);
    if (lane == 0) Hex = 0.f;
    Hin[idx] = Hex;
}

__global__ __launch_bounds__(256) void scan_pass3(const u16* __restrict__ ip,
                                                  const u16* __restrict__ fp,
                                                  const float* __restrict__ Hin,
                                                  u16* __restrict__ hout) {
    const int tid = blockIdx.x * 256 + threadIdx.x;  // 65536 threads
    const int d4  = tid & 255;
    const int c   = (tid >> 8) & (NC - 1);
    const int b   = tid >> 14;
    size_t base = ((size_t)(b * TT + c * CT) << 10) + (size_t)d4 * 4;
    const size_t o = (((size_t)(b * NC + c)) << 10) + (size_t)d4 * 4;
    float4 hv = *(const float4*)(Hin + o);
    float h[4] = {hv.x, hv.y, hv.z, hv.w};
#pragma unroll 8
    for (int t = 0; t < CT; t++) {
        ushort4 fu = *(const ushort4*)(fp + base);
        ushort4 iu = *(const ushort4*)(ip + base);
        const u16 fa[4] = {fu.x, fu.y, fu.z, fu.w};
        const u16 ia[4] = {iu.x, iu.y, iu.z, iu.w};
        ushort4 ou;
        u16 oa[4];
#pragma unroll
        for (int j = 0; j < 4; j++) {
            float f  = sigm(bf2f(fa[j]));
            float iv = bf2f(ia[j]);
            float v  = iv * sigm(iv) * (1.f - f);
            h[j] = fmaf(f, h[j], v);
            oa[j] = f2bf(h[j]);
        }
        ou.x = oa[0]; ou.y = oa[1]; ou.z = oa[2]; ou.w = oa[3];
        *(ushort4*)(hout + base) = ou;
        base += DD;
    }
}

// ---------------------------------------------------------------- RMSNorm * swish(g)
__global__ __launch_bounds__(256) void rmsnorm_gate(const u16* hin,
                                                    const u16* __restrict__ g,
                                                    const float* __restrict__ w,
                                                    u16* oout) {
    const int row = blockIdx.x;
    const int t = threadIdx.x;
    const size_t base = ((size_t)row << 10) + t * 4;
    ushort4 hu = *(const ushort4*)(hin + base);
    float h0 = bf2f(hu.x), h1 = bf2f(hu.y), h2 = bf2f(hu.z), h3 = bf2f(hu.w);
    float ss = h0 * h0 + h1 * h1 + h2 * h2 + h3 * h3;
#pragma unroll
    for (int o = 32; o > 0; o >>= 1) ss += __shfl_down(ss, o);
    __shared__ float red[4];
    if ((t & 63) == 0) red[t >> 6] = ss;
    __syncthreads();
    const float tot = red[0] + red[1] + red[2] + red[3];
    const float rms = rsqrtf(tot * (1.f / 1024.f) + 1e-5f);
    ushort4 gu = *(const ushort4*)(g + base);
    float g0 = bf2f(gu.x), g1 = bf2f(gu.y), g2 = bf2f(gu.z), g3 = bf2f(gu.w);
    float4 wv = *(const float4*)(w + (size_t)t * 4);
    ushort4 ou;
    ou.x = f2bf(h0 * rms * wv.x * g0 * sigm(g0));
    ou.y = f2bf(h1 * rms * wv.y * g1 * sigm(g1));
    ou.z = f2bf(h2 * rms * wv.z * g2 * sigm(g2));
    ou.w = f2bf(h3 * rms * wv.w * g3 * sigm(g3));
    *(ushort4*)(oout + base) = ou;
}

// ---------------------------------------------------------------- launch
extern "C" void kernel_launch(void* const* d_in, const int* in_sizes, int n_in,
                              void* d_out, int out_size, void* d_ws, size_t ws_size,
                              hipStream_t stream) {
    const float* x  = (const float*)d_in[0];
    const float* Wi = (const float*)d_in[1];
    const float* Wf = (const float*)d_in[2];
    const float* Wg = (const float*)d_in[3];
    const float* Wo = (const float*)d_in[4];
    const float* nw = (const float*)d_in[5];
    float* out = (float*)d_out;

    const size_t MB = 1ull << 20;
    char* ws = (char*)d_ws;
    u16*   xo  = (u16*)(ws);              // 32MB: x_bf16, later h_bf16 then o_bf16
    u16*   Wb  = (u16*)(ws + 32 * MB);    // 8MB: [Wi;Wf;Wg;Wo] bf16, K-major rows
    u16*   Pi  = (u16*)(ws + 40 * MB);    // 32MB: i_pre bf16
    u16*   Pf  = (u16*)(ws + 72 * MB);    // 32MB: f_pre bf16
    float* Fc  = (float*)(ws + 104 * MB); // 1MB
    float* Ic  = Fc + BB * NC * DD;       // 1MB
    float* Hin = Ic + BB * NC * DD;       // 1MB
    u16*   g   = (u16*)d_out;             // g plane (bf16) parked in d_out until final GEMM

    conv_x_kernel<<<16384, 256, 0, stream>>>(x, xo);
    conv_w4_kernel<<<4096, 256, 0, stream>>>(Wi, Wf, Wg, Wo, Wb);
    // i_pre / f_pre / g in one GEMM: N=3072 (8-phase 256^2 asm kernel)
    gemm256a<u16><<<dim3(12, 64), 512, 0, stream>>>(xo, Wb, 1024, Pi, Pf, g);
    scan_pass1<<<256, 256, 0, stream>>>(Pi, Pf, Fc, Ic);
    scan_pass2<<<1024, 256, 0, stream>>>(Fc, Ic, Hin);
    scan_pass3<<<256, 256, 0, stream>>>(Pi, Pf, Hin, xo);
    rmsnorm_gate<<<16384, 256, 0, stream>>>(xo, g, nw, xo);
    // out = o @ Wo^T (proven 128^2 kernel; doubles as machine-speed reference in trace)
    gemm_bf16_bt<float><<<dim3(8, 128), 256, 0, stream>>>(xo, Wb + 3ull * 1024 * 1024, 1024,
                                                          out, out, out);
}